// Round 4
// baseline (303.142 us; speedup 1.0000x reference)
//
#include <hip/hip_runtime.h>
#include <hip/hip_bf16.h>
#include <stdint.h>

#define BB 2
#define SS 2048
#define DMM 2048
#define HH 16
#define DHH 128

typedef unsigned short u16;
typedef __attribute__((ext_vector_type(8))) short bf16x8;
typedef __attribute__((ext_vector_type(8))) unsigned short u16x8;
typedef __attribute__((ext_vector_type(4))) float f32x4;

#define WAITV(N) asm volatile("s_waitcnt vmcnt(" #N ")" ::: "memory")
#define WAITLGKM(N) asm volatile("s_waitcnt lgkmcnt(" #N ")" ::: "memory")
#define SCHEDBAR __builtin_amdgcn_sched_barrier(0)

__device__ __forceinline__ u16 f2bf(float f) {
  union { float f; uint32_t u; } v; v.f = f;
  return (u16)((v.u + 0x7FFFu + ((v.u >> 16) & 1u)) >> 16);  // RNE
}

__device__ __forceinline__ void stage16(const void* g, void* l) {
  __builtin_amdgcn_global_load_lds(
      (const __attribute__((address_space(1))) void*)g,
      (__attribute__((address_space(3))) void*)l, 16, 0, 0);
}

// ---------------- f32 -> bf16 convert, 8 elems/thread ----------------
__global__ void cvt_bf16_k(const float* __restrict__ in, u16* __restrict__ out) {
  size_t i = (size_t)blockIdx.x * blockDim.x + threadIdx.x;
  const float4* p = (const float4*)in + i * 2;
  float4 a = p[0], b = p[1];
  u16x8 v;
  v[0] = f2bf(a.x); v[1] = f2bf(a.y); v[2] = f2bf(a.z); v[3] = f2bf(a.w);
  v[4] = f2bf(b.x); v[5] = f2bf(b.y); v[6] = f2bf(b.z); v[7] = f2bf(b.w);
  *((u16x8*)out + i) = v;
}

// ================= 256x256-tile 4-phase GEMM with read-early =================
// ds_reads for phase p are issued during phase p-1's MFMA window and drained
// with COUNTED lgkmcnt (LDS analog of T4) so the LDS unit works under MFMA:
//   q3(T): WAITV(8); issue bf0(T+1)[8]; MFMA q3(af0*bf1)     <- drain under MFMA
//   q0(T): issue af0[4]+af1[4]; stage B1(T+1); bar; lgkm(4); MFMA q0(af0*bf0)
//   q1(T): WAITV(10); issue bf1[8]; stage A0(T+2); bar; lgkm(8); MFMA q1(af1*bf0)
//   q2(T): stage A1(T+2); bar; lgkm(0); MFMA q2(af1*bf1)
// Wait audit (stage-halves, 2 loads each):
//   WAITV(8)@q3(T) leaves newest4 {B1(T+1),A0(T+2),A1(T+2),B0(T+2)} ->
//     B0(T+1) + all of tile T's stages retired before bf0(T+1)/af*(T) reads.
//   WAITV(10)@q1(T) leaves newest5 -> B1(T) retired before bf1(T) reads.
// Region overwrites: every region's readers drain at an lgkm before a barrier
// that precedes the overwriting stage (af0@q0-lgkm4 < A0-stage@q1; af1@q1-lgkm8
// < A1-stage@q2; bf0@q0-lgkm4 < B0-stage@q3; bf1@q2-lgkm0 < B1-stage@q0(T+1)).
__global__ __launch_bounds__(512, 2)
void gemm_qkv8_k(const u16* __restrict__ A, const u16* __restrict__ Bm,
                 const float* __restrict__ bias,
                 const float* __restrict__ fcr, const float* __restrict__ fci,
                 u16* __restrict__ Qo, u16* __restrict__ Ko, u16* __restrict__ Vto,
                 int Kdim)
{
  const int tid = threadIdx.x;
  const int lane = tid & 63, w = tid >> 6, g = lane >> 4, c = lane & 15;
  const int wm = w >> 1, wn = w & 1;

  // XCD chunking, bm-fast: each XCD owns 3 bn-panels (3MB B in L2), streams A.
  const int nwg = gridDim.x * gridDim.y;
  int flat = blockIdx.y * gridDim.x + blockIdx.x;
  flat = (flat & 7) * (nwg >> 3) + (flat >> 3);
  const int bm = flat % gridDim.y;
  const int bn = flat / gridDim.y;

  __shared__ __align__(16) u16 As[2][256 * 64];
  __shared__ __align__(16) u16 Bs[2][256 * 64];

  f32x4 acc[4][8] = {};

  const long K2 = (long)Kdim * 2;
  const char* Abase = (const char*)A + ((long)bm * 256) * K2;
  const char* Bbase = (const char*)Bm + ((long)bn * 256) * K2;
  const int nt = Kdim >> 6;

  // permuted halves: A half0 = rows {wmblk*64+0..31}, half1 = +32;
  // B half0 = rows {wnblk*128+0..63}, half1 = +64. 16KB per half, 2 loads/thr.
  auto stageA = [&](int kb, u16* buf, int half) {
    #pragma unroll
    for (int i = 0; i < 2; ++i) {
      int off = half * 16384 + i * 8192 + tid * 16;
      int rl = off >> 7, cb2 = off & 127;
      int cbs = cb2 ^ ((rl & 7) << 4);
      int rm = ((rl >> 5) & 3) * 64 + half * 32 + (rl & 31);
      stage16(Abase + (long)rm * K2 + kb * 2 + cbs, (char*)buf + off);
    }
  };
  auto stageB = [&](int kb, u16* buf, int half) {
    #pragma unroll
    for (int i = 0; i < 2; ++i) {
      int off = half * 16384 + i * 8192 + tid * 16;
      int rl = off >> 7, cb2 = off & 127;
      int cbs = cb2 ^ ((rl & 7) << 4);
      int rm = ((rl >> 6) & 1) * 128 + half * 64 + (rl & 63);
      stage16(Bbase + (long)rm * K2 + kb * 2 + cbs, (char*)buf + off);
    }
  };
  auto ldr = [&](const u16* buf, int rl, int cb) -> bf16x8 {
    int ab = (rl << 7) + (cb ^ ((rl & 7) << 4));
    return *(const bf16x8*)((const char*)buf + ab);
  };

  bf16x8 af0[2][2], af1[2][2], bf0[2][4], bf1[2][4];

  // prologue: t0.{A0,A1,B0,B1}, t1.{A0,A1,B0}; WAITV(8) retires t0.{A0,A1,B0}
  stageA(0, As[0], 0); stageA(0, As[0], 1); stageB(0, Bs[0], 0);
  stageB(0, Bs[0], 1);
  stageA(64, As[1], 0); stageA(64, As[1], 1); stageB(64, Bs[1], 0);
  WAITV(8);
  __builtin_amdgcn_s_barrier();
  // pre-read bf0(t0) (the q3-early read of the pipeline)
  #pragma unroll
  for (int kc = 0; kc < 2; ++kc)
    #pragma unroll
    for (int n = 0; n < 4; ++n)
      bf0[kc][n] = ldr(Bs[0], wn * 64 + n * 16 + c, kc * 64 + g * 16);

  for (int t = 0; t < nt; ++t) {
    const int cur = t & 1;
    u16* Ac = As[cur];
    u16* Bc = Bs[cur];
    const int kb1 = (t + 1) << 6, kb2 = (t + 2) << 6;

    // ---- q0: issue af0+af1; stage (t+1).B1; lgkm(4); MFMA Q(0,0) ----
    #pragma unroll
    for (int kc = 0; kc < 2; ++kc)
      #pragma unroll
      for (int m = 0; m < 2; ++m)
        af0[kc][m] = ldr(Ac, wm * 32 + m * 16 + c, kc * 64 + g * 16);
    #pragma unroll
    for (int kc = 0; kc < 2; ++kc)
      #pragma unroll
      for (int m = 0; m < 2; ++m)
        af1[kc][m] = ldr(Ac, 128 + wm * 32 + m * 16 + c, kc * 64 + g * 16);
    if (t + 1 < nt) stageB(kb1, Bs[cur ^ 1], 1);
    __builtin_amdgcn_s_barrier();
    WAITLGKM(4); SCHEDBAR;          // af0,bf0 ready; af1 drains under MFMA
    __builtin_amdgcn_s_setprio(1);
    #pragma unroll
    for (int kc = 0; kc < 2; ++kc)
      #pragma unroll
      for (int m = 0; m < 2; ++m)
        #pragma unroll
        for (int n = 0; n < 4; ++n)
          acc[m][n] = __builtin_amdgcn_mfma_f32_16x16x32_bf16(af0[kc][m], bf0[kc][n], acc[m][n], 0, 0, 0);
    __builtin_amdgcn_s_setprio(0);
    __builtin_amdgcn_s_barrier();

    // ---- q1: WAITV(10); issue bf1; stage (t+2).A0; lgkm(8); MFMA Q(1,0) ----
    if (t < nt - 3) { WAITV(10); } else { WAITV(0); }   // retires B1(t)
    #pragma unroll
    for (int kc = 0; kc < 2; ++kc)
      #pragma unroll
      for (int n = 0; n < 4; ++n)
        bf1[kc][n] = ldr(Bc, 128 + wn * 64 + n * 16 + c, kc * 64 + g * 16);
    if (t + 2 < nt) stageA(kb2, Ac, 0);
    __builtin_amdgcn_s_barrier();
    WAITLGKM(8); SCHEDBAR;          // af1 ready; bf1 drains under MFMA
    __builtin_amdgcn_s_setprio(1);
    #pragma unroll
    for (int kc = 0; kc < 2; ++kc)
      #pragma unroll
      for (int m = 0; m < 2; ++m)
        #pragma unroll
        for (int n = 0; n < 4; ++n)
          acc[2 + m][n] = __builtin_amdgcn_mfma_f32_16x16x32_bf16(af1[kc][m], bf0[kc][n], acc[2 + m][n], 0, 0, 0);
    __builtin_amdgcn_s_setprio(0);
    __builtin_amdgcn_s_barrier();

    // ---- q2: stage (t+2).A1; lgkm(0); MFMA Q(1,1) ----
    if (t + 2 < nt) stageA(kb2, Ac, 1);
    __builtin_amdgcn_s_barrier();
    WAITLGKM(0); SCHEDBAR;          // bf1 ready
    __builtin_amdgcn_s_setprio(1);
    #pragma unroll
    for (int kc = 0; kc < 2; ++kc)
      #pragma unroll
      for (int m = 0; m < 2; ++m)
        #pragma unroll
        for (int n = 0; n < 4; ++n)
          acc[2 + m][4 + n] = __builtin_amdgcn_mfma_f32_16x16x32_bf16(af1[kc][m], bf1[kc][n], acc[2 + m][4 + n], 0, 0, 0);
    __builtin_amdgcn_s_setprio(0);
    __builtin_amdgcn_s_barrier();

    // ---- q3: stage (t+2).B0; WAITV(8); issue bf0(t+1); MFMA Q(0,1) ----
    if (t + 2 < nt) stageB(kb2, Bc, 0);
    __builtin_amdgcn_s_barrier();
    if (t < nt - 3) { WAITV(8); } else { WAITV(0); }    // retires (t+1) stages
    if (t + 1 < nt) {
      #pragma unroll
      for (int kc = 0; kc < 2; ++kc)
        #pragma unroll
        for (int n = 0; n < 4; ++n)
          bf0[kc][n] = ldr(Bs[cur ^ 1], wn * 64 + n * 16 + c, kc * 64 + g * 16);
    }
    SCHEDBAR;                        // pin reads before MFMA (drain under it)
    __builtin_amdgcn_s_setprio(1);
    #pragma unroll
    for (int kc = 0; kc < 2; ++kc)
      #pragma unroll
      for (int m = 0; m < 2; ++m)
        #pragma unroll
        for (int n = 0; n < 4; ++n)
          acc[m][4 + n] = __builtin_amdgcn_mfma_f32_16x16x32_bf16(af0[kc][m], bf1[kc][n], acc[m][4 + n], 0, 0, 0);
    __builtin_amdgcn_s_setprio(0);
    __builtin_amdgcn_s_barrier();
  }

  // ---- epilogue: bias + rope + scatter ----
  const int sec = bn * 2 + wn;          // 0..47 (16 Q, 16 K, 16 V sections)
  const int kind = sec >> 4, h = sec & 15;
  const int rowb = bm * 256 + wm * 64;
  if (kind < 2) {
    const float scale = (kind == 0) ? 0.08838834764831845f : 1.0f;  // DH^-0.5 in Q
    u16* O = (kind == 0) ? Qo : Ko;
    #pragma unroll
    for (int nf = 0; nf < 4; ++nf) {
      int d = nf * 16 + c;
      float fr = fcr[h * 64 + d], fi = fci[h * 64 + d];  // per-HEAD angle (ref quirk)
      float bre = bias[sec * 128 + d], bim = bias[sec * 128 + 64 + d];
      #pragma unroll
      for (int mf = 0; mf < 4; ++mf)
        #pragma unroll
        for (int j = 0; j < 4; ++j) {
          int row = rowb + mf * 16 + g * 4 + j;
          int s = row & (SS - 1), b = row >> 11;
          float re = acc[mf][nf][j] + bre;
          float im = acc[mf][nf + 4][j] + bim;
          long base = (((long)(b * HH + h)) * SS + s) * DHH;
          O[base + d]      = f2bf((re * fr - im * fi) * scale);
          O[base + 64 + d] = f2bf((re * fi + im * fr) * scale);
        }
    }
  } else {
    #pragma unroll
    for (int nf = 0; nf < 8; ++nf) {
      int d = nf * 16 + c;
      float bv = bias[sec * 128 + d];
      #pragma unroll
      for (int mf = 0; mf < 4; ++mf)
        #pragma unroll
        for (int j = 0; j < 4; ++j) {
          int row = rowb + mf * 16 + g * 4 + j;
          int s = row & (SS - 1), b = row >> 11;
          Vto[(((long)(b * HH + h)) * DHH + d) * SS + s] = f2bf(acc[mf][nf][j] + bv);
        }
    }
  }
}

// ---------------- 128x128-tile GEMM (out-proj, unchanged) ----------------
template<int MODE>
__global__ __launch_bounds__(256)
void gemm_bt_k(const u16* __restrict__ A, const u16* __restrict__ Bm,
               const float* __restrict__ bias,
               float* __restrict__ Fo,
               int Ndim, int Kdim)
{
  const int tid = threadIdx.x;
  const int lane = tid & 63, w = tid >> 6, g = lane >> 4, c = lane & 15;
  const int bn = blockIdx.x, bm = blockIdx.y;

  __shared__ __align__(16) u16 As[128 * 64];
  __shared__ __align__(16) u16 Bs[128 * 64];

  constexpr int MF = 4;
  constexpr int NF = 4;
  const int wrow = (w >> 1) * 64;
  const int wcol = (w & 1) * 64;

  f32x4 acc[MF][NF] = {};

  const char* Abase = (const char*)A + ((long)bm * 128) * Kdim * 2;
  const char* Bbase = (const char*)Bm + ((long)bn * 128) * Kdim * 2;
  const int wub = w * 1024;

  for (int kb = 0; kb < Kdim; kb += 64) {
    #pragma unroll
    for (int i = 0; i < 4; ++i) {
      int ob = i * 4096 + wub;
      int o = ob + (lane << 4);
      int r = o >> 7, cb = o & 127;
      int cbs = cb ^ ((r & 7) << 4);
      stage16(Abase + ((long)r * Kdim + kb) * 2 + cbs, (char*)As + ob);
    }
    #pragma unroll
    for (int i = 0; i < 4; ++i) {
      int ob = i * 4096 + wub;
      int o = ob + (lane << 4);
      int r = o >> 7, cb = o & 127;
      int cbs = cb ^ ((r & 7) << 4);
      stage16(Bbase + ((long)r * Kdim + kb) * 2 + cbs, (char*)Bs + ob);
    }
    __syncthreads();
    #pragma unroll
    for (int kc = 0; kc < 2; ++kc) {
      bf16x8 af[MF], bfr[NF];
      #pragma unroll
      for (int mf = 0; mf < MF; ++mf) {
        int r = wrow + mf * 16 + c;
        int ab = (r << 7) + kc * 64 + (g << 4);
        ab ^= (r & 7) << 4;
        af[mf] = *(const bf16x8*)((const char*)As + ab);
      }
      #pragma unroll
      for (int nf = 0; nf < NF; ++nf) {
        int r = wcol + nf * 16 + c;
        int ab = (r << 7) + kc * 64 + (g << 4);
        ab ^= (r & 7) << 4;
        bfr[nf] = *(const bf16x8*)((const char*)Bs + ab);
      }
      #pragma unroll
      for (int mf = 0; mf < MF; ++mf)
        #pragma unroll
        for (int nf = 0; nf < NF; ++nf)
          acc[mf][nf] = __builtin_amdgcn_mfma_f32_16x16x32_bf16(af[mf], bfr[nf], acc[mf][nf], 0, 0, 0);
    }
    __syncthreads();
  }

  #pragma unroll
  for (int mf = 0; mf < MF; ++mf)
    #pragma unroll
    for (int nf = 0; nf < NF; ++nf) {
      int col = bn * 128 + wcol + nf * 16 + c;
      float bv = bias[col];
      #pragma unroll
      for (int j = 0; j < 4; ++j) {
        int row = bm * 128 + wrow + mf * 16 + g * 4 + j;
        Fo[(long)row * Ndim + col] = acc[mf][nf][j] + bv;
      }
    }
}

// ---------------- causal flash attention (unchanged) ----------------
__global__ __launch_bounds__(256)
void attn_k(const u16* __restrict__ Q, const u16* __restrict__ K,
            const u16* __restrict__ Vt, u16* __restrict__ Ao)
{
  const int tid = threadIdx.x;
  const int lane = tid & 63, w = tid >> 6, g = lane >> 4, c = lane & 15;
  const int bh = blockIdx.x;
  const int qt = (int)(gridDim.y - 1 - blockIdx.y);
  const int b = bh >> 4, h = bh & 15;
  const int qbase = qt * 64;

  __shared__ __align__(16) u16 Ks[64 * 128];
  __shared__ __align__(16) u16 Vts[128 * 64];
  __shared__ __align__(16) u16 Ps[4][16 * 64];

  const long head = (long)bh * SS * DHH;

  bf16x8 qf[4];
  {
    const u16* qp = Q + head + (long)(qbase + w * 16 + c) * DHH + g * 8;
    #pragma unroll
    for (int kc = 0; kc < 4; ++kc) qf[kc] = *(const bf16x8*)(qp + kc * 32);
  }

  f32x4 o[8] = {};
  float m[4], l[4];
  #pragma unroll
  for (int j = 0; j < 4; ++j) { m[j] = -INFINITY; l[j] = 0.f; }

  const int wub = w * 1024;
  for (int t = 0; t <= qt; ++t) {
    const int kvbase = t * 64;
    #pragma unroll
    for (int i = 0; i < 4; ++i) {
      int ob = i * 4096 + wub;
      int o_ = ob + (lane << 4);
      int r = o_ >> 8, cb = o_ & 255;
      int cbs = cb ^ ((r & 7) << 4);
      stage16((const char*)(K + head) + (long)(kvbase + r) * 256 + cbs, (char*)Ks + ob);
    }
    #pragma unroll
    for (int i = 0; i < 4; ++i) {
      int ob = i * 4096 + wub;
      int o_ = ob + (lane << 4);
      int r = o_ >> 7, cb = o_ & 127;
      int cbs = cb ^ ((r & 7) << 4);
      stage16((const char*)(Vt + head) + (long)r * (SS * 2) + kvbase * 2 + cbs, (char*)Vts + ob);
    }
    __syncthreads();

    f32x4 sf[4];
    #pragma unroll
    for (int nf = 0; nf < 4; ++nf) {
      f32x4 s = {0.f, 0.f, 0.f, 0.f};
      #pragma unroll
      for (int kc = 0; kc < 4; ++kc) {
        int r = nf * 16 + c;
        int ab = (r << 8) + kc * 64 + (g << 4);
        ab ^= (r & 7) << 4;
        bf16x8 kf = *(const bf16x8*)((const char*)Ks + ab);
        s = __builtin_amdgcn_mfma_f32_16x16x32_bf16(qf[kc], kf, s, 0, 0, 0);
      }
      sf[nf] = s;
    }

    if (t == qt) {
      #pragma unroll
      for (int nf = 0; nf < 4; ++nf)
        #pragma unroll
        for (int j = 0; j < 4; ++j)
          if (nf * 16 + c > w * 16 + g * 4 + j) sf[nf][j] = -INFINITY;
    }

    float mn[4], cf[4], rs[4];
    #pragma unroll
    for (int j = 0; j < 4; ++j) {
      float v = fmaxf(fmaxf(sf[0][j], sf[1][j]), fmaxf(sf[2][j], sf[3][j]));
      v = fmaxf(v, __shfl_xor(v, 1));
      v = fmaxf(v, __shfl_xor(v, 2));
      v = fmaxf(v, __shfl_xor(v, 4));
      v = fmaxf(v, __shfl_xor(v, 8));
      mn[j] = fmaxf(m[j], v);
      cf[j] = exp2f((m[j] - mn[j]) * 1.4426950408889634f);
      m[j] = mn[j];
      rs[j] = 0.f;
    }
    #pragma unroll
    for (int nf = 0; nf < 4; ++nf)
      #pragma unroll
      for (int j = 0; j < 4; ++j) {
        float p = exp2f((sf[nf][j] - mn[j]) * 1.4426950408889634f);
        sf[nf][j] = p;
        rs[j] += p;
      }
    #pragma unroll
    for (int j = 0; j < 4; ++j) {
      float v = rs[j];
      v += __shfl_xor(v, 1); v += __shfl_xor(v, 2);
      v += __shfl_xor(v, 4); v += __shfl_xor(v, 8);
      l[j] = l[j] * cf[j] + v;
    }
    #pragma unroll
    for (int nf = 0; nf < 8; ++nf)
      #pragma unroll
      for (int j = 0; j < 4; ++j)
        o[nf][j] *= cf[j];

    #pragma unroll
    for (int nf = 0; nf < 4; ++nf)
      #pragma unroll
      for (int j = 0; j < 4; ++j) {
        int pr = g * 4 + j;
        int ab = (pr << 7) + (nf * 16 + c) * 2;
        ab ^= (pr & 7) << 4;
        *(u16*)((char*)Ps[w] + ab) = f2bf(sf[nf][j]);
      }

    bf16x8 pf[2];
    #pragma unroll
    for (int kc = 0; kc < 2; ++kc) {
      int ab = (c << 7) + kc * 64 + (g << 4);
      ab ^= (c & 7) << 4;
      pf[kc] = *(const bf16x8*)((const char*)Ps[w] + ab);
    }
    #pragma unroll
    for (int nf = 0; nf < 8; ++nf) {
      #pragma unroll
      for (int kc = 0; kc < 2; ++kc) {
        int r = nf * 16 + c;
        int ab = (r << 7) + kc * 64 + (g << 4);
        ab ^= (r & 7) << 4;
        bf16x8 vf = *(const bf16x8*)((const char*)Vts + ab);
        o[nf] = __builtin_amdgcn_mfma_f32_16x16x32_bf16(pf[kc], vf, o[nf], 0, 0, 0);
      }
    }
    __syncthreads();
  }

  #pragma unroll
  for (int j = 0; j < 4; ++j) {
    float inv = 1.0f / l[j];
    int row = qbase + w * 16 + g * 4 + j;
    long ob = ((long)(b * SS + row)) * DMM + h * DHH;
    #pragma unroll
    for (int nf = 0; nf < 8; ++nf)
      Ao[ob + nf * 16 + c] = f2bf(o[nf][j] * inv);
  }
}

extern "C" void kernel_launch(void* const* d_in, const int* in_sizes, int n_in,
                              void* d_out, int out_size, void* d_ws, size_t ws_size,
                              hipStream_t stream) {
  const float* x     = (const float*)d_in[0];
  const float* w_qkv = (const float*)d_in[1];
  const float* b_qkv = (const float*)d_in[2];
  const float* w_out = (const float*)d_in[3];
  const float* b_out = (const float*)d_in[4];
  const float* fcr   = (const float*)d_in[5];
  const float* fci   = (const float*)d_in[6];
  float* outp = (float*)d_out;

  char* ws = (char*)d_ws;               // needs 96 MB
  u16* xb  = (u16*)(ws + 0);            // 16MB x bf16 [4096][2048]
  u16* wqb = (u16*)(ws + (16L << 20));  // 24MB w_qkv bf16 [6144][2048]
  u16* wob = (u16*)(ws + (40L << 20));  // 8MB  w_out bf16 [2048][2048]
  u16* Qb  = (u16*)(ws + (48L << 20));  // 16MB [bh][s][128] (scaled+roped)
  u16* Kb  = (u16*)(ws + (64L << 20));  // 16MB [bh][s][128] (roped)
  u16* Vtb = (u16*)(ws + (80L << 20));  // 16MB [bh][128][s]
  u16* attno = xb;                      // alias: xb dead after GEMM1

  cvt_bf16_k<<<4096, 256, 0, stream>>>(x, xb);
  cvt_bf16_k<<<6144, 256, 0, stream>>>(w_qkv, wqb);
  cvt_bf16_k<<<2048, 256, 0, stream>>>(w_out, wob);

  gemm_qkv8_k<<<dim3(24, 16), 512, 0, stream>>>(
      xb, wqb, b_qkv, fcr, fci, Qb, Kb, Vtb, 2048);

  attn_k<<<dim3(32, 32), 256, 0, stream>>>(Qb, Kb, Vtb, attno);

  gemm_bt_k<1><<<dim3(16, 32), 256, 0, stream>>>(
      attno, wob, b_out, outp, 2048, 2048);
}

// Round 5
// 271.406 us; speedup vs baseline: 1.1169x; 1.1169x over previous
//
#include <hip/hip_runtime.h>
#include <hip/hip_bf16.h>
#include <stdint.h>

#define BB 2
#define SS 2048
#define DMM 2048
#define HH 16
#define DHH 128

typedef unsigned short u16;
typedef __attribute__((ext_vector_type(8))) short bf16x8;
typedef __attribute__((ext_vector_type(8))) unsigned short u16x8;
typedef __attribute__((ext_vector_type(4))) float f32x4;

#define WAITV(N) asm volatile("s_waitcnt vmcnt(" #N ")" ::: "memory")
#define BARRIER asm volatile("s_barrier" ::: "memory")

__device__ __forceinline__ u16 f2bf(float f) {
  union { float f; uint32_t u; } v; v.f = f;
  return (u16)((v.u + 0x7FFFu + ((v.u >> 16) & 1u)) >> 16);  // RNE
}

__device__ __forceinline__ void stage16(const void* g, void* l) {
  __builtin_amdgcn_global_load_lds(
      (const __attribute__((address_space(1))) void*)g,
      (__attribute__((address_space(3))) void*)l, 16, 0, 0);
}

// ---------------- f32 -> bf16 convert, 8 elems/thread ----------------
__global__ void cvt_bf16_k(const float* __restrict__ in, u16* __restrict__ out) {
  size_t i = (size_t)blockIdx.x * blockDim.x + threadIdx.x;
  const float4* p = (const float4*)in + i * 2;
  float4 a = p[0], b = p[1];
  u16x8 v;
  v[0] = f2bf(a.x); v[1] = f2bf(a.y); v[2] = f2bf(a.z); v[3] = f2bf(a.w);
  v[4] = f2bf(b.x); v[5] = f2bf(b.y); v[6] = f2bf(b.z); v[7] = f2bf(b.w);
  *((u16x8*)out + i) = v;
}

// ------------- 128x128-tile GEMM, C = A[M][K]*B[N][K]^T, prefetch-pipelined -------------
// T3-minimum: stage(t+1) into buf^1 issued BEFORE compute(t); counted WAITV(8)
// keeps the 8 prefetch loads in flight across the (raw, memory-clobber) barrier.
// MODE 0: epilogue = +bias, per-head rope (fc indexed by HEAD per reference),
//         scatter Q (scaled) / K [bh][s][128] / V^T [bh][128][s]
// MODE 1: epilogue = +bias, f32 row-major out
template<int MODE>
__global__ __launch_bounds__(256)
void gemm_bt_k(const u16* __restrict__ A, const u16* __restrict__ Bm,
               const float* __restrict__ bias,
               const float* __restrict__ fcr, const float* __restrict__ fci,
               u16* __restrict__ Qo, u16* __restrict__ Ko, u16* __restrict__ Vto,
               float* __restrict__ Fo,
               int Ndim, int Kdim)
{
  const int tid = threadIdx.x;
  const int lane = tid & 63, w = tid >> 6, g = lane >> 4, c = lane & 15;
  const int bn = blockIdx.x, bm = blockIdx.y;

  __shared__ __align__(16) u16 As[2][128 * 64];
  __shared__ __align__(16) u16 Bs[2][128 * 64];

  constexpr int MF = (MODE == 0) ? 2 : 4;
  constexpr int NF = (MODE == 0) ? 8 : 4;
  const int wrow = (MODE == 0) ? w * 32 : (w >> 1) * 64;
  const int wcol = (MODE == 0) ? 0 : (w & 1) * 64;

  f32x4 acc[MF][NF] = {};

  const char* Abase = (const char*)A + ((long)bm * 128) * Kdim * 2;
  const char* Bbase = (const char*)Bm + ((long)bn * 128) * Kdim * 2;
  const int wub = w * 1024;

  // 4 A-loads + 4 B-loads per thread per tile (16B each), linear LDS dest +
  // inverse-swizzled global source (rule #21)
  auto stage_tile = [&](int kb, int buf) {
    #pragma unroll
    for (int i = 0; i < 4; ++i) {
      int ob = i * 4096 + wub;
      int o = ob + (lane << 4);
      int r = o >> 7, cb = o & 127;
      int cbs = cb ^ ((r & 7) << 4);
      stage16(Abase + ((long)r * Kdim + kb) * 2 + cbs, (char*)As[buf] + ob);
    }
    #pragma unroll
    for (int i = 0; i < 4; ++i) {
      int ob = i * 4096 + wub;
      int o = ob + (lane << 4);
      int r = o >> 7, cb = o & 127;
      int cbs = cb ^ ((r & 7) << 4);
      stage16(Bbase + ((long)r * Kdim + kb) * 2 + cbs, (char*)Bs[buf] + ob);
    }
  };

  stage_tile(0, 0);
  WAITV(0);
  BARRIER;

  const int nt = Kdim >> 6;
  for (int t = 0; t < nt; ++t) {
    const int cur = t & 1;
    if (t + 1 < nt) { stage_tile((t + 1) << 6, cur ^ 1); WAITV(8); }
    else            { WAITV(0); }

    #pragma unroll
    for (int kc = 0; kc < 2; ++kc) {
      bf16x8 af[MF], bfr[NF];
      #pragma unroll
      for (int mf = 0; mf < MF; ++mf) {
        int r = wrow + mf * 16 + c;
        int ab = (r << 7) + kc * 64 + (g << 4);
        ab ^= (r & 7) << 4;
        af[mf] = *(const bf16x8*)((const char*)As[cur] + ab);
      }
      #pragma unroll
      for (int nf = 0; nf < NF; ++nf) {
        int r = wcol + nf * 16 + c;
        int ab = (r << 7) + kc * 64 + (g << 4);
        ab ^= (r & 7) << 4;
        bfr[nf] = *(const bf16x8*)((const char*)Bs[cur] + ab);
      }
      #pragma unroll
      for (int mf = 0; mf < MF; ++mf)
        #pragma unroll
        for (int nf = 0; nf < NF; ++nf)
          acc[mf][nf] = __builtin_amdgcn_mfma_f32_16x16x32_bf16(af[mf], bfr[nf], acc[mf][nf], 0, 0, 0);
    }
    BARRIER;   // readers of buf done -> next iter may overwrite it
  }

  if constexpr (MODE == 1) {
    #pragma unroll
    for (int mf = 0; mf < MF; ++mf)
      #pragma unroll
      for (int nf = 0; nf < NF; ++nf) {
        int col = bn * 128 + wcol + nf * 16 + c;
        float bv = bias[col];
        #pragma unroll
        for (int j = 0; j < 4; ++j) {
          int row = bm * 128 + wrow + mf * 16 + g * 4 + j;
          Fo[(long)row * Ndim + col] = acc[mf][nf][j] + bv;
        }
      }
  } else {
    const int sec = bn >> 4, h = bn & 15, b = bm >> 4;
    if (sec < 2) {
      // Q or K head tile: rope pairs are frags (nf, nf+4) in the same lane
      const float scale = (sec == 0) ? 0.08838834764831845f : 1.0f;  // DH^-0.5 in Q
      u16* O = (sec == 0) ? Qo : Ko;
      #pragma unroll
      for (int nf = 0; nf < 4; ++nf) {
        int d = nf * 16 + c;
        float fr = fcr[h * 64 + d], fi = fci[h * 64 + d];  // per-HEAD angle (ref quirk)
        float bre = bias[bn * 128 + d], bim = bias[bn * 128 + 64 + d];
        #pragma unroll
        for (int mf = 0; mf < MF; ++mf)
          #pragma unroll
          for (int j = 0; j < 4; ++j) {
            int row = bm * 128 + wrow + mf * 16 + g * 4 + j;
            int s = row & (SS - 1);
            float re = acc[mf][nf][j] + bre;
            float im = acc[mf][nf + 4][j] + bim;
            long base = (((long)(b * HH + h)) * SS + s) * DHH;
            O[base + d]      = f2bf((re * fr - im * fi) * scale);
            O[base + 64 + d] = f2bf((re * fi + im * fr) * scale);
          }
      }
    } else {
      // V tile -> transposed layout [bh][d][s]
      #pragma unroll
      for (int nf = 0; nf < 8; ++nf) {
        int d = nf * 16 + c;
        float bv = bias[bn * 128 + d];
        #pragma unroll
        for (int mf = 0; mf < MF; ++mf)
          #pragma unroll
          for (int j = 0; j < 4; ++j) {
            int row = bm * 128 + wrow + mf * 16 + g * 4 + j;
            int s = row & (SS - 1);
            Vto[(((long)(b * HH + h)) * DHH + d) * SS + s] = f2bf(acc[mf][nf][j] + bv);
          }
      }
    }
  }
}

// ---------------- causal flash attention, prefetch-pipelined ----------------
// grid: (bh=32, qtiles=32), block 256 = 4 waves x 16 q-rows, KVBLK=64.
// K/V double-buffered (64KB) + wave-private P (8KB) = 72KB -> 2 blocks/CU.
// stage(t+1) issued before compute(t); WAITV(8) leaves prefetch in flight.
__global__ __launch_bounds__(256)
void attn_k(const u16* __restrict__ Q, const u16* __restrict__ K,
            const u16* __restrict__ Vt, u16* __restrict__ Ao)
{
  const int tid = threadIdx.x;
  const int lane = tid & 63, w = tid >> 6, g = lane >> 4, c = lane & 15;
  const int bh = blockIdx.x;
  const int qt = (int)(gridDim.y - 1 - blockIdx.y);  // heavy tiles dispatch first
  const int b = bh >> 4, h = bh & 15;
  const int qbase = qt * 64;

  __shared__ __align__(16) u16 Ks[2][64 * 128];    // rows 256B, XOR-swizzled
  __shared__ __align__(16) u16 Vts[2][128 * 64];   // [dh][kv], rows 128B, swizzled
  __shared__ __align__(16) u16 Ps[4][16 * 64];     // wave-private P, swizzled

  const long head = (long)bh * SS * DHH;
  const int wub = w * 1024;

  auto stage_tile = [&](int t, int buf) {
    const int kvbase = t * 64;
    #pragma unroll
    for (int i = 0; i < 4; ++i) {  // K tile 64x128
      int ob = i * 4096 + wub;
      int o_ = ob + (lane << 4);
      int r = o_ >> 8, cb = o_ & 255;
      int cbs = cb ^ ((r & 7) << 4);
      stage16((const char*)(K + head) + (long)(kvbase + r) * 256 + cbs, (char*)Ks[buf] + ob);
    }
    #pragma unroll
    for (int i = 0; i < 4; ++i) {  // Vt tile 128x64
      int ob = i * 4096 + wub;
      int o_ = ob + (lane << 4);
      int r = o_ >> 7, cb = o_ & 127;
      int cbs = cb ^ ((r & 7) << 4);
      stage16((const char*)(Vt + head) + (long)r * (SS * 2) + kvbase * 2 + cbs, (char*)Vts[buf] + ob);
    }
  };

  bf16x8 qf[4];  // Q rows already scaled by DH^-0.5
  {
    const u16* qp = Q + head + (long)(qbase + w * 16 + c) * DHH + g * 8;
    #pragma unroll
    for (int kc = 0; kc < 4; ++kc) qf[kc] = *(const bf16x8*)(qp + kc * 32);
  }

  f32x4 o[8] = {};
  float m[4], l[4];
  #pragma unroll
  for (int j = 0; j < 4; ++j) { m[j] = -INFINITY; l[j] = 0.f; }

  stage_tile(0, 0);
  WAITV(0);
  BARRIER;

  for (int t = 0; t <= qt; ++t) {
    const int cur = t & 1;
    if (t < qt) { stage_tile(t + 1, cur ^ 1); WAITV(8); }
    else        { WAITV(0); }

    // S = Q K^T (per wave: 16 q-rows x 64 kv)
    f32x4 sf[4];
    __builtin_amdgcn_s_setprio(1);
    #pragma unroll
    for (int nf = 0; nf < 4; ++nf) {
      f32x4 s = {0.f, 0.f, 0.f, 0.f};
      #pragma unroll
      for (int kc = 0; kc < 4; ++kc) {
        int r = nf * 16 + c;
        int ab = (r << 8) + kc * 64 + (g << 4);
        ab ^= (r & 7) << 4;
        bf16x8 kf = *(const bf16x8*)((const char*)Ks[cur] + ab);
        s = __builtin_amdgcn_mfma_f32_16x16x32_bf16(qf[kc], kf, s, 0, 0, 0);
      }
      sf[nf] = s;
    }
    __builtin_amdgcn_s_setprio(0);

    if (t == qt) {  // diagonal tile: strict causal mask
      #pragma unroll
      for (int nf = 0; nf < 4; ++nf)
        #pragma unroll
        for (int j = 0; j < 4; ++j)
          if (nf * 16 + c > w * 16 + g * 4 + j) sf[nf][j] = -INFINITY;
    }

    // online softmax (rows live on 16-lane groups, reduce over lane&15)
    float mn[4], cf[4], rs[4];
    #pragma unroll
    for (int j = 0; j < 4; ++j) {
      float v = fmaxf(fmaxf(sf[0][j], sf[1][j]), fmaxf(sf[2][j], sf[3][j]));
      v = fmaxf(v, __shfl_xor(v, 1));
      v = fmaxf(v, __shfl_xor(v, 2));
      v = fmaxf(v, __shfl_xor(v, 4));
      v = fmaxf(v, __shfl_xor(v, 8));
      mn[j] = fmaxf(m[j], v);
      cf[j] = exp2f((m[j] - mn[j]) * 1.4426950408889634f);
      m[j] = mn[j];
      rs[j] = 0.f;
    }
    #pragma unroll
    for (int nf = 0; nf < 4; ++nf)
      #pragma unroll
      for (int j = 0; j < 4; ++j) {
        float p = exp2f((sf[nf][j] - mn[j]) * 1.4426950408889634f);
        sf[nf][j] = p;
        rs[j] += p;
      }
    #pragma unroll
    for (int j = 0; j < 4; ++j) {
      float v = rs[j];
      v += __shfl_xor(v, 1); v += __shfl_xor(v, 2);
      v += __shfl_xor(v, 4); v += __shfl_xor(v, 8);
      l[j] = l[j] * cf[j] + v;
    }
    #pragma unroll
    for (int nf = 0; nf < 8; ++nf)
      #pragma unroll
      for (int j = 0; j < 4; ++j)
        o[nf][j] *= cf[j];

    // P -> wave-private LDS (C-layout -> A-layout redistribution)
    #pragma unroll
    for (int nf = 0; nf < 4; ++nf)
      #pragma unroll
      for (int j = 0; j < 4; ++j) {
        int pr = g * 4 + j;
        int ab = (pr << 7) + (nf * 16 + c) * 2;
        ab ^= (pr & 7) << 4;
        *(u16*)((char*)Ps[w] + ab) = f2bf(sf[nf][j]);
      }

    // O += P V
    bf16x8 pf[2];
    #pragma unroll
    for (int kc = 0; kc < 2; ++kc) {
      int ab = (c << 7) + kc * 64 + (g << 4);
      ab ^= (c & 7) << 4;
      pf[kc] = *(const bf16x8*)((const char*)Ps[w] + ab);
    }
    __builtin_amdgcn_s_setprio(1);
    #pragma unroll
    for (int nf = 0; nf < 8; ++nf) {
      #pragma unroll
      for (int kc = 0; kc < 2; ++kc) {
        int r = nf * 16 + c;
        int ab = (r << 7) + kc * 64 + (g << 4);
        ab ^= (r & 7) << 4;
        bf16x8 vf = *(const bf16x8*)((const char*)Vts[cur] + ab);
        o[nf] = __builtin_amdgcn_mfma_f32_16x16x32_bf16(pf[kc], vf, o[nf], 0, 0, 0);
      }
    }
    __builtin_amdgcn_s_setprio(0);
    BARRIER;   // readers of buf done -> next iter may overwrite it
  }

  #pragma unroll
  for (int j = 0; j < 4; ++j) {
    float inv = 1.0f / l[j];
    int row = qbase + w * 16 + g * 4 + j;
    long ob = ((long)(b * SS + row)) * DMM + h * DHH;
    #pragma unroll
    for (int nf = 0; nf < 8; ++nf)
      Ao[ob + nf * 16 + c] = f2bf(o[nf][j] * inv);
  }
}

extern "C" void kernel_launch(void* const* d_in, const int* in_sizes, int n_in,
                              void* d_out, int out_size, void* d_ws, size_t ws_size,
                              hipStream_t stream) {
  const float* x     = (const float*)d_in[0];
  const float* w_qkv = (const float*)d_in[1];
  const float* b_qkv = (const float*)d_in[2];
  const float* w_out = (const float*)d_in[3];
  const float* b_out = (const float*)d_in[4];
  const float* fcr   = (const float*)d_in[5];
  const float* fci   = (const float*)d_in[6];
  // d_in[7] mask: causal triu(k=1), hardcoded in attn_k
  float* outp = (float*)d_out;

  char* ws = (char*)d_ws;               // needs 96 MB
  u16* xb  = (u16*)(ws + 0);            // 16MB x bf16 [4096][2048]
  u16* wqb = (u16*)(ws + (16L << 20));  // 24MB w_qkv bf16 [6144][2048]
  u16* wob = (u16*)(ws + (40L << 20));  // 8MB  w_out bf16 [2048][2048]
  u16* Qb  = (u16*)(ws + (48L << 20));  // 16MB [bh][s][128] (scaled+roped)
  u16* Kb  = (u16*)(ws + (64L << 20));  // 16MB [bh][s][128] (roped)
  u16* Vtb = (u16*)(ws + (80L << 20));  // 16MB [bh][128][s]
  u16* attno = xb;                      // alias: xb dead after GEMM1

  cvt_bf16_k<<<4096, 256, 0, stream>>>(x, xb);
  cvt_bf16_k<<<6144, 256, 0, stream>>>(w_qkv, wqb);
  cvt_bf16_k<<<2048, 256, 0, stream>>>(w_out, wob);

  gemm_bt_k<0><<<dim3(48, 32), 256, 0, stream>>>(
      xb, wqb, b_qkv, fcr, fci, Qb, Kb, Vtb, nullptr, 6144, 2048);

  attn_k<<<dim3(32, 32), 256, 0, stream>>>(Qb, Kb, Vtb, attno);

  gemm_bt_k<1><<<dim3(16, 32), 256, 0, stream>>>(
      attno, wob, b_out, nullptr, nullptr, nullptr, nullptr, nullptr, outp,
      2048, 2048);
}

// Round 6
// 266.002 us; speedup vs baseline: 1.1396x; 1.0203x over previous
//
#include <hip/hip_runtime.h>
#include <hip/hip_bf16.h>
#include <stdint.h>

#define BB 2
#define SS 2048
#define DMM 2048
#define HH 16
#define DHH 128

typedef unsigned short u16;
typedef __attribute__((ext_vector_type(8))) short bf16x8;
typedef __attribute__((ext_vector_type(8))) unsigned short u16x8;
typedef __attribute__((ext_vector_type(4))) float f32x4;

#define WAITV(N) asm volatile("s_waitcnt vmcnt(" #N ")" ::: "memory")
#define BARRIER asm volatile("s_barrier" ::: "memory")

__device__ __forceinline__ u16 f2bf(float f) {
  union { float f; uint32_t u; } v; v.f = f;
  return (u16)((v.u + 0x7FFFu + ((v.u >> 16) & 1u)) >> 16);  // RNE
}

__device__ __forceinline__ void stage16(const void* g, void* l) {
  __builtin_amdgcn_global_load_lds(
      (const __attribute__((address_space(1))) void*)g,
      (__attribute__((address_space(3))) void*)l, 16, 0, 0);
}

// ---------------- fused f32 -> bf16 converts (x, w_qkv, w_out) ----------------
__global__ void cvt_bf16_k(const float* __restrict__ s0, u16* __restrict__ d0,
                           const float* __restrict__ s1, u16* __restrict__ d1,
                           const float* __restrict__ s2, u16* __restrict__ d2) {
  int bid = blockIdx.x;
  const float* src; u16* dst; size_t base;
  if (bid < 4096)       { src = s0; dst = d0; base = (size_t)bid; }
  else if (bid < 10240) { src = s1; dst = d1; base = (size_t)(bid - 4096); }
  else                  { src = s2; dst = d2; base = (size_t)(bid - 10240); }
  size_t i = base * 256 + threadIdx.x;
  const float4* p = (const float4*)src + i * 2;
  float4 a = p[0], b = p[1];
  u16x8 v;
  v[0] = f2bf(a.x); v[1] = f2bf(a.y); v[2] = f2bf(a.z); v[3] = f2bf(a.w);
  v[4] = f2bf(b.x); v[5] = f2bf(b.y); v[6] = f2bf(b.z); v[7] = f2bf(b.w);
  *((u16x8*)dst + i) = v;
}

// B-row permutation for MODE 0: LDS row p holds matrix row f(p) so that rope
// pairs (d, d+64) land in the SAME lane as frag pair (nf even, nf odd).
__device__ __forceinline__ int bperm(int p) {
  return ((p >> 5) << 4) + (p & 15) + (((p >> 4) & 1) << 6);
}

// ------------- 128x128-tile GEMM, C = A[M][K]*B[N][K]^T, prefetch-pipelined -------------
// 4 waves as 2x2, wave tile 64x64 (MF=NF=4): 16 ds_read_b128/wave/iter.
// stage(t+1) issued BEFORE compute(t); counted WAITV(8) keeps prefetch in
// flight across the raw barrier (T3-minimum).
// MODE 0: B rows staged with bperm; epilogue = +bias, per-head rope (fc indexed
//         by HEAD per reference), scatter Q(scaled)/K [bh][s][128], V^T [bh][128][s]
// MODE 1: epilogue = +bias, f32 row-major out
template<int MODE>
__global__ __launch_bounds__(256)
void gemm_bt_k(const u16* __restrict__ A, const u16* __restrict__ Bm,
               const float* __restrict__ bias,
               const float* __restrict__ fcr, const float* __restrict__ fci,
               u16* __restrict__ Qo, u16* __restrict__ Ko, u16* __restrict__ Vto,
               float* __restrict__ Fo,
               int Ndim, int Kdim)
{
  const int tid = threadIdx.x;
  const int lane = tid & 63, w = tid >> 6, g = lane >> 4, c = lane & 15;

  // XCD-chunked swizzle, bm-grouped: each XCD keeps 4 A-panels (2MB) L2-hot
  // and streams B panels (shared by its 4 concurrent bm blocks).
  const int f = blockIdx.y * gridDim.x + blockIdx.x;
  const int xcd = f & 7, idx = f >> 3;
  const int bm = xcd * 4 + (idx & 3);
  const int bn = idx >> 2;

  __shared__ __align__(16) u16 As[2][128 * 64];
  __shared__ __align__(16) u16 Bs[2][128 * 64];

  const int wrow = (w >> 1) * 64;
  const int wcol = (w & 1) * 64;

  f32x4 acc[4][4] = {};

  const char* Abase = (const char*)A + ((long)bm * 128) * Kdim * 2;
  const char* Bbase = (const char*)Bm + ((long)bn * 128) * Kdim * 2;
  const int wub = w * 1024;

  // 4 A-loads + 4 B-loads per thread per tile (16B each), linear LDS dest +
  // inverse-swizzled (and for MODE 0 B: inverse-permuted) global source
  auto stage_tile = [&](int kb, int buf) {
    #pragma unroll
    for (int i = 0; i < 4; ++i) {
      int ob = i * 4096 + wub;
      int o = ob + (lane << 4);
      int r = o >> 7, cb = o & 127;
      int cbs = cb ^ ((r & 7) << 4);
      stage16(Abase + ((long)r * Kdim + kb) * 2 + cbs, (char*)As[buf] + ob);
    }
    #pragma unroll
    for (int i = 0; i < 4; ++i) {
      int ob = i * 4096 + wub;
      int o = ob + (lane << 4);
      int r = o >> 7, cb = o & 127;
      int cbs = cb ^ ((r & 7) << 4);
      int rg = (MODE == 0) ? bperm(r) : r;
      stage16(Bbase + ((long)rg * Kdim + kb) * 2 + cbs, (char*)Bs[buf] + ob);
    }
  };

  stage_tile(0, 0);
  WAITV(0);
  BARRIER;

  const int nt = Kdim >> 6;
  for (int t = 0; t < nt; ++t) {
    const int cur = t & 1;
    if (t + 1 < nt) { stage_tile((t + 1) << 6, cur ^ 1); WAITV(8); }
    else            { WAITV(0); }

    #pragma unroll
    for (int kc = 0; kc < 2; ++kc) {
      bf16x8 af[4], bfr[4];
      #pragma unroll
      for (int mf = 0; mf < 4; ++mf) {
        int r = wrow + mf * 16 + c;
        int ab = (r << 7) + kc * 64 + (g << 4);
        ab ^= (r & 7) << 4;
        af[mf] = *(const bf16x8*)((const char*)As[cur] + ab);
      }
      #pragma unroll
      for (int nf = 0; nf < 4; ++nf) {
        int r = wcol + nf * 16 + c;
        int ab = (r << 7) + kc * 64 + (g << 4);
        ab ^= (r & 7) << 4;
        bfr[nf] = *(const bf16x8*)((const char*)Bs[cur] + ab);
      }
      #pragma unroll
      for (int mf = 0; mf < 4; ++mf)
        #pragma unroll
        for (int nf = 0; nf < 4; ++nf)
          acc[mf][nf] = __builtin_amdgcn_mfma_f32_16x16x32_bf16(af[mf], bfr[nf], acc[mf][nf], 0, 0, 0);
    }
    BARRIER;   // readers of buf done -> next iter may overwrite it
  }

  if constexpr (MODE == 1) {
    #pragma unroll
    for (int mf = 0; mf < 4; ++mf)
      #pragma unroll
      for (int nf = 0; nf < 4; ++nf) {
        int col = bn * 128 + wcol + nf * 16 + c;
        float bv = bias[col];
        #pragma unroll
        for (int j = 0; j < 4; ++j) {
          int row = bm * 128 + wrow + mf * 16 + g * 4 + j;
          Fo[(long)row * Ndim + col] = acc[mf][nf][j] + bv;
        }
      }
  } else {
    const int sec = bn >> 4, h = bn & 15, b = bm >> 4;
    if (sec < 2) {
      // Q/K: rope pairs (d, d+64) = frag pair (nf even, nf odd), same lane
      const float scale = (sec == 0) ? 0.08838834764831845f : 1.0f;  // DH^-0.5 in Q
      u16* O = (sec == 0) ? Qo : Ko;
      #pragma unroll
      for (int pe = 0; pe < 2; ++pe) {
        int nfr = pe * 2, nfi = nfr + 1;
        int p = wcol + nfr * 16 + c;          // parity 0 -> real part
        int d = ((p >> 5) << 4) + (p & 15);   // bperm with im-bit 0
        float fr = fcr[h * 64 + d], fi = fci[h * 64 + d];  // per-HEAD angle (ref quirk)
        float bre = bias[bn * 128 + d], bim = bias[bn * 128 + 64 + d];
        #pragma unroll
        for (int mf = 0; mf < 4; ++mf)
          #pragma unroll
          for (int j = 0; j < 4; ++j) {
            int row = bm * 128 + wrow + mf * 16 + g * 4 + j;
            int s = row & (SS - 1);
            float re = acc[mf][nfr][j] + bre;
            float im = acc[mf][nfi][j] + bim;
            long base = (((long)(b * HH + h)) * SS + s) * DHH;
            O[base + d]      = f2bf((re * fr - im * fi) * scale);
            O[base + 64 + d] = f2bf((re * fi + im * fr) * scale);
          }
      }
    } else {
      // V tile -> transposed layout [bh][d][s] (any col perm fine, use bperm map)
      #pragma unroll
      for (int nf = 0; nf < 4; ++nf) {
        int p = wcol + nf * 16 + c;
        int d = bperm(p);
        float bv = bias[bn * 128 + d];
        #pragma unroll
        for (int mf = 0; mf < 4; ++mf)
          #pragma unroll
          for (int j = 0; j < 4; ++j) {
            int row = bm * 128 + wrow + mf * 16 + g * 4 + j;
            int s = row & (SS - 1);
            Vto[(((long)(b * HH + h)) * DHH + d) * SS + s] = f2bf(acc[mf][nf][j] + bv);
          }
      }
    }
  }
}

// ---------------- causal flash attention, prefetch-pipelined ----------------
// grid: 1024 linear; XCD-chunked: each XCD owns 4 bh (2MB K/V L2-resident),
// qt heavy-first within XCD. block 256 = 4 waves x 16 q-rows, KVBLK=64.
__global__ __launch_bounds__(256)
void attn_k(const u16* __restrict__ Q, const u16* __restrict__ K,
            const u16* __restrict__ Vt, u16* __restrict__ Ao)
{
  const int tid = threadIdx.x;
  const int lane = tid & 63, w = tid >> 6, g = lane >> 4, c = lane & 15;
  const int f = blockIdx.x;
  const int xcd = f & 7, idx = f >> 3;          // idx 0..127
  const int bh = xcd * 4 + (idx & 3);           // 4 bh per XCD
  const int qt = 31 - (idx >> 2);               // heavy tiles first
  const int b = bh >> 4, h = bh & 15;
  const int qbase = qt * 64;

  __shared__ __align__(16) u16 Ks[2][64 * 128];    // rows 256B, XOR-swizzled
  __shared__ __align__(16) u16 Vts[2][128 * 64];   // [dh][kv], rows 128B, swizzled
  __shared__ __align__(16) u16 Ps[4][16 * 64];     // wave-private P, swizzled

  const long head = (long)bh * SS * DHH;
  const int wub = w * 1024;

  auto stage_tile = [&](int t, int buf) {
    const int kvbase = t * 64;
    #pragma unroll
    for (int i = 0; i < 4; ++i) {  // K tile 64x128
      int ob = i * 4096 + wub;
      int o_ = ob + (lane << 4);
      int r = o_ >> 8, cb = o_ & 255;
      int cbs = cb ^ ((r & 7) << 4);
      stage16((const char*)(K + head) + (long)(kvbase + r) * 256 + cbs, (char*)Ks[buf] + ob);
    }
    #pragma unroll
    for (int i = 0; i < 4; ++i) {  // Vt tile 128x64
      int ob = i * 4096 + wub;
      int o_ = ob + (lane << 4);
      int r = o_ >> 7, cb = o_ & 127;
      int cbs = cb ^ ((r & 7) << 4);
      stage16((const char*)(Vt + head) + (long)r * (SS * 2) + kvbase * 2 + cbs, (char*)Vts[buf] + ob);
    }
  };

  bf16x8 qf[4];  // Q rows already scaled by DH^-0.5
  {
    const u16* qp = Q + head + (long)(qbase + w * 16 + c) * DHH + g * 8;
    #pragma unroll
    for (int kc = 0; kc < 4; ++kc) qf[kc] = *(const bf16x8*)(qp + kc * 32);
  }

  f32x4 o[8] = {};
  float m[4], l[4];
  #pragma unroll
  for (int j = 0; j < 4; ++j) { m[j] = -INFINITY; l[j] = 0.f; }

  stage_tile(0, 0);
  WAITV(0);
  BARRIER;

  for (int t = 0; t <= qt; ++t) {
    const int cur = t & 1;
    if (t < qt) { stage_tile(t + 1, cur ^ 1); WAITV(8); }
    else        { WAITV(0); }

    // S = Q K^T (per wave: 16 q-rows x 64 kv)
    f32x4 sf[4];
    __builtin_amdgcn_s_setprio(1);
    #pragma unroll
    for (int nf = 0; nf < 4; ++nf) {
      f32x4 s = {0.f, 0.f, 0.f, 0.f};
      #pragma unroll
      for (int kc = 0; kc < 4; ++kc) {
        int r = nf * 16 + c;
        int ab = (r << 8) + kc * 64 + (g << 4);
        ab ^= (r & 7) << 4;
        bf16x8 kf = *(const bf16x8*)((const char*)Ks[cur] + ab);
        s = __builtin_amdgcn_mfma_f32_16x16x32_bf16(qf[kc], kf, s, 0, 0, 0);
      }
      sf[nf] = s;
    }
    __builtin_amdgcn_s_setprio(0);

    if (t == qt) {  // diagonal tile: strict causal mask
      #pragma unroll
      for (int nf = 0; nf < 4; ++nf)
        #pragma unroll
        for (int j = 0; j < 4; ++j)
          if (nf * 16 + c > w * 16 + g * 4 + j) sf[nf][j] = -INFINITY;
    }

    // online softmax (rows live on 16-lane groups, reduce over lane&15)
    float mn[4], cf[4], rs[4];
    #pragma unroll
    for (int j = 0; j < 4; ++j) {
      float v = fmaxf(fmaxf(sf[0][j], sf[1][j]), fmaxf(sf[2][j], sf[3][j]));
      v = fmaxf(v, __shfl_xor(v, 1));
      v = fmaxf(v, __shfl_xor(v, 2));
      v = fmaxf(v, __shfl_xor(v, 4));
      v = fmaxf(v, __shfl_xor(v, 8));
      mn[j] = fmaxf(m[j], v);
      cf[j] = exp2f((m[j] - mn[j]) * 1.4426950408889634f);
      m[j] = mn[j];
      rs[j] = 0.f;
    }
    #pragma unroll
    for (int nf = 0; nf < 4; ++nf)
      #pragma unroll
      for (int j = 0; j < 4; ++j) {
        float p = exp2f((sf[nf][j] - mn[j]) * 1.4426950408889634f);
        sf[nf][j] = p;
        rs[j] += p;
      }
    #pragma unroll
    for (int j = 0; j < 4; ++j) {
      float v = rs[j];
      v += __shfl_xor(v, 1); v += __shfl_xor(v, 2);
      v += __shfl_xor(v, 4); v += __shfl_xor(v, 8);
      l[j] = l[j] * cf[j] + v;
    }
    #pragma unroll
    for (int nf = 0; nf < 8; ++nf)
      #pragma unroll
      for (int j = 0; j < 4; ++j)
        o[nf][j] *= cf[j];

    // P -> wave-private LDS (C-layout -> A-layout redistribution)
    #pragma unroll
    for (int nf = 0; nf < 4; ++nf)
      #pragma unroll
      for (int j = 0; j < 4; ++j) {
        int pr = g * 4 + j;
        int ab = (pr << 7) + (nf * 16 + c) * 2;
        ab ^= (pr & 7) << 4;
        *(u16*)((char*)Ps[w] + ab) = f2bf(sf[nf][j]);
      }

    // O += P V
    bf16x8 pf[2];
    #pragma unroll
    for (int kc = 0; kc < 2; ++kc) {
      int ab = (c << 7) + kc * 64 + (g << 4);
      ab ^= (c & 7) << 4;
      pf[kc] = *(const bf16x8*)((const char*)Ps[w] + ab);
    }
    __builtin_amdgcn_s_setprio(1);
    #pragma unroll
    for (int nf = 0; nf < 8; ++nf) {
      #pragma unroll
      for (int kc = 0; kc < 2; ++kc) {
        int r = nf * 16 + c;
        int ab = (r << 7) + kc * 64 + (g << 4);
        ab ^= (r & 7) << 4;
        bf16x8 vf = *(const bf16x8*)((const char*)Vts[cur] + ab);
        o[nf] = __builtin_amdgcn_mfma_f32_16x16x32_bf16(pf[kc], vf, o[nf], 0, 0, 0);
      }
    }
    __builtin_amdgcn_s_setprio(0);
    BARRIER;   // readers of buf done -> next iter may overwrite it
  }

  #pragma unroll
  for (int j = 0; j < 4; ++j) {
    float inv = 1.0f / l[j];
    int row = qbase + w * 16 + g * 4 + j;
    long ob = ((long)(b * SS + row)) * DMM + h * DHH;
    #pragma unroll
    for (int nf = 0; nf < 8; ++nf)
      Ao[ob + nf * 16 + c] = f2bf(o[nf][j] * inv);
  }
}

extern "C" void kernel_launch(void* const* d_in, const int* in_sizes, int n_in,
                              void* d_out, int out_size, void* d_ws, size_t ws_size,
                              hipStream_t stream) {
  const float* x     = (const float*)d_in[0];
  const float* w_qkv = (const float*)d_in[1];
  const float* b_qkv = (const float*)d_in[2];
  const float* w_out = (const float*)d_in[3];
  const float* b_out = (const float*)d_in[4];
  const float* fcr   = (const float*)d_in[5];
  const float* fci   = (const float*)d_in[6];
  // d_in[7] mask: causal triu(k=1), hardcoded in attn_k
  float* outp = (float*)d_out;

  char* ws = (char*)d_ws;               // needs 96 MB
  u16* xb  = (u16*)(ws + 0);            // 16MB x bf16 [4096][2048]
  u16* wqb = (u16*)(ws + (16L << 20));  // 24MB w_qkv bf16 [6144][2048]
  u16* wob = (u16*)(ws + (40L << 20));  // 8MB  w_out bf16 [2048][2048]
  u16* Qb  = (u16*)(ws + (48L << 20));  // 16MB [bh][s][128] (scaled+roped)
  u16* Kb  = (u16*)(ws + (64L << 20));  // 16MB [bh][s][128] (roped)
  u16* Vtb = (u16*)(ws + (80L << 20));  // 16MB [bh][128][s]
  u16* attno = xb;                      // alias: xb dead after GEMM1

  cvt_bf16_k<<<12288, 256, 0, stream>>>(x, xb, w_qkv, wqb, w_out, wob);

  gemm_bt_k<0><<<dim3(48, 32), 256, 0, stream>>>(
      xb, wqb, b_qkv, fcr, fci, Qb, Kb, Vtb, nullptr, 6144, 2048);

  attn_k<<<1024, 256, 0, stream>>>(Qb, Kb, Vtb, attno);

  gemm_bt_k<1><<<dim3(16, 32), 256, 0, stream>>>(
      attno, wob, b_out, nullptr, nullptr, nullptr, nullptr, nullptr, outp,
      2048, 2048);
}